// Round 3
// baseline (970.387 us; speedup 1.0000x reference)
//
#include <hip/hip_runtime.h>

#define NU 100000      // N_USERS
#define NE 100000      // N_ENTITIES
#define NN 200000      // N_NODES
#define EKG 1500000
#define EPR 1500000
#define NNZI 1000000
#define D 64

#define GCN_ENT_BASE (NU * D)
#define NODE_BASE    (NN * D)

// destination-range partitioning (8 partitions ~ 8 XCDs)
#define PKG 12500      // ceil(NE/8)
#define PPR 25000      // ceil(NN/8)
#define PIT 12500      // ceil(NU/8)
#define CHUNK 4096
#define NCHUNK ((EKG + CHUNK - 1) / CHUNK)   // 367

// block counts for scans (1024-element chunks)
#define NB_KG 98     // ceil(NE/1024)
#define NB_PR 196    // ceil(NN/1024)
#define NB_IT 98     // ceil(NU/1024)
#define BS_KG 0
#define BS_PR 128
#define BS_IT 384

__device__ __forceinline__ float wave_sum_f(float v) {
    v += __shfl_xor(v, 32);
    v += __shfl_xor(v, 16);
    v += __shfl_xor(v, 8);
    v += __shfl_xor(v, 4);
    v += __shfl_xor(v, 2);
    v += __shfl_xor(v, 1);
    return v;
}

__device__ __forceinline__ int wave_sum_i(int v) {
    v += __shfl_xor(v, 32);
    v += __shfl_xor(v, 16);
    v += __shfl_xor(v, 8);
    v += __shfl_xor(v, 4);
    v += __shfl_xor(v, 2);
    v += __shfl_xor(v, 1);
    return v;
}

// ---------------- CSR build (XCD-partitioned by destination range) ----------------

__global__ void k_hist_part(const int* __restrict__ kg_head, const int* __restrict__ pr_head,
                            const int* __restrict__ it_row,
                            int* __restrict__ deg_kg, int* __restrict__ deg_pr, int* __restrict__ deg_it) {
    int part = blockIdx.x & 7;
    int chunk = blockIdx.x >> 3;
    int base = chunk * CHUNK;
    int end = base + CHUNK; if (end > EKG) end = EKG;
    int lo_kg = part * PKG, lo_pr = part * PPR, lo_it = part * PIT;
    for (int i = base + threadIdx.x; i < end; i += 256) {
        int h = kg_head[i];
        if ((unsigned)(h - lo_kg) < PKG) atomicAdd(&deg_kg[h], 1);
        int h2 = pr_head[i];
        if ((unsigned)(h2 - lo_pr) < PPR) atomicAdd(&deg_pr[h2], 1);
        if (i < NNZI) {
            int r = it_row[i];
            if ((unsigned)(r - lo_it) < PIT) atomicAdd(&deg_it[r], 1);
        }
    }
}

__global__ void k_place_part(const int* __restrict__ kg_head, const int* __restrict__ kg_tail,
                             const int* __restrict__ kg_type,
                             const int* __restrict__ pr_head, const int* __restrict__ pr_tail,
                             const int* __restrict__ pr_type,
                             const int* __restrict__ it_row, const int* __restrict__ it_col,
                             const float* __restrict__ it_val,
                             int* __restrict__ cur_kg, int* __restrict__ cur_pr, int* __restrict__ cur_it,
                             int* __restrict__ csr_kg, int* __restrict__ csr_pr,
                             int2* __restrict__ csr_icv) {
    int part = blockIdx.x & 7;
    int chunk = blockIdx.x >> 3;
    int base = chunk * CHUNK;
    int end = base + CHUNK; if (end > EKG) end = EKG;
    int lo_kg = part * PKG, lo_pr = part * PPR, lo_it = part * PIT;
    for (int i = base + threadIdx.x; i < end; i += 256) {
        int h = kg_head[i];
        if ((unsigned)(h - lo_kg) < PKG) {
            int pos = atomicAdd(&cur_kg[h], 1);
            csr_kg[pos] = kg_tail[i] | ((kg_type[i] - 1) << 17);   // tail<2^17, rel 0..15
        }
        int h2 = pr_head[i];
        if ((unsigned)(h2 - lo_pr) < PPR) {
            int pos = atomicAdd(&cur_pr[h2], 1);
            csr_pr[pos] = pr_tail[i] | (pr_type[i] << 18);          // tail<2^18, type 0..31
        }
        if (i < NNZI) {
            int r = it_row[i];
            if ((unsigned)(r - lo_it) < PIT) {
                int pos = atomicAdd(&cur_it[r], 1);
                csr_icv[pos] = make_int2(it_col[i], __float_as_int(it_val[i]));
            }
        }
    }
}

// ---------------- scans ----------------

__global__ void k_blocksum3(const int* __restrict__ ckg, const int* __restrict__ cpr,
                            const int* __restrict__ cit, int* __restrict__ bsum) {
    __shared__ int wsum[4];
    int bid = blockIdx.x;
    const int* cnt; int n; int* outp;
    if (bid < NB_KG)              { cnt = ckg; n = NE; outp = bsum + BS_KG + bid; }
    else if (bid < NB_KG + NB_PR) { bid -= NB_KG; cnt = cpr; n = NN; outp = bsum + BS_PR + bid; }
    else                          { bid -= NB_KG + NB_PR; cnt = cit; n = NU; outp = bsum + BS_IT + bid; }
    int base = bid * 1024;
    int s = 0;
    for (int k = threadIdx.x; k < 1024; k += 256) {
        int i = base + k;
        s += (i < n) ? cnt[i] : 0;
    }
    s = wave_sum_i(s);
    int wid = threadIdx.x >> 6;
    if ((threadIdx.x & 63) == 0) wsum[wid] = s;
    __syncthreads();
    if (threadIdx.x == 0) *outp = wsum[0] + wsum[1] + wsum[2] + wsum[3];
}

__global__ void k_scansums3(int* __restrict__ bsum, int* __restrict__ tkg,
                            int* __restrict__ tpr, int* __restrict__ tit) {
    if (threadIdx.x != 0) return;
    int* seg; int nb; int* tot;
    if (blockIdx.x == 0)      { seg = bsum + BS_KG; nb = NB_KG; tot = tkg; }
    else if (blockIdx.x == 1) { seg = bsum + BS_PR; nb = NB_PR; tot = tpr; }
    else                      { seg = bsum + BS_IT; nb = NB_IT; tot = tit; }
    int acc = 0;
    for (int b = 0; b < nb; b++) { int v = seg[b]; seg[b] = acc; acc += v; }
    *tot = acc;
}

__global__ void k_scanfinal3(const int* __restrict__ ckg, const int* __restrict__ cpr,
                             const int* __restrict__ cit, const int* __restrict__ bsum,
                             int* __restrict__ okg, int* __restrict__ opr, int* __restrict__ oit,
                             int* __restrict__ rkg, int* __restrict__ rpr, int* __restrict__ rit) {
    __shared__ int buf[1024];
    int bid = blockIdx.x;
    const int* cnt; int n; const int* boff; int* off; int* cur;
    if (bid < NB_KG)              { cnt = ckg; n = NE; boff = bsum + BS_KG; off = okg; cur = rkg; }
    else if (bid < NB_KG + NB_PR) { bid -= NB_KG; cnt = cpr; n = NN; boff = bsum + BS_PR; off = opr; cur = rpr; }
    else                          { bid -= NB_KG + NB_PR; cnt = cit; n = NU; boff = bsum + BS_IT; off = oit; cur = rit; }
    int i = bid * 1024 + threadIdx.x;
    int v = (i < n) ? cnt[i] : 0;
    int x = v;
    buf[threadIdx.x] = x;
    __syncthreads();
    for (int d = 1; d < 1024; d <<= 1) {
        int t = (threadIdx.x >= d) ? buf[threadIdx.x - d] : 0;
        __syncthreads();
        x += t;
        buf[threadIdx.x] = x;
        __syncthreads();
    }
    if (i < n) {
        int excl = x - v + boff[bid];
        off[i] = excl;
        cur[i] = excl;
    }
}

// ---------------- output init ----------------
__global__ void k_init(const float* __restrict__ user, const float* __restrict__ ent,
                       float* __restrict__ out) {
    int i = blockIdx.x * blockDim.x + threadIdx.x;
    if (i >= NU * D) return;
    float u = user[i];
    float e = ent[i];
    out[i] = u;                            // user_res accumulator
    out[NODE_BASE + i] = u;                // node_res user part
    out[NODE_BASE + NU * D + i] = e;       // node_res entity part
}

// ---------------- aggregation ----------------
// Wave layout: 4 edge-subgroups (sub = lane>>4) x 16 lanes (d4 = lane&15),
// each lane handles one float4 (4 dims) of the 64-dim row. 8 edges in flight
// per serial step (two independent chains per subgroup).

__global__ void k_agg_entity(const float4* __restrict__ src, const float4* __restrict__ w,
                             const int* __restrict__ off, const int* __restrict__ csr,
                             float4* __restrict__ raw, float4* __restrict__ nrm) {
    int lane = threadIdx.x & 63;
    int sub = lane >> 4, d4 = lane & 15;
    int row = blockIdx.x * (blockDim.x >> 6) + (threadIdx.x >> 6);
    if (row >= NE) return;
    int s = off[row], e = off[row + 1];
    float4 acc = make_float4(0.f, 0.f, 0.f, 0.f);
    for (int base = s; base < e; base += 64) {
        int m = e - base; if (m > 64) m = 64;
        int p = (lane < m) ? csr[base + lane] : 0;
        int kmax = (m + 7) >> 3;
        for (int k = 0; k < kmax; k++) {
            int ei0 = (k << 3) + sub;
            int ei1 = ei0 + 4;
            int pk0 = __shfl(p, ei0);
            int pk1 = __shfl(p, ei1);
            if (ei0 < m) {
                int t = pk0 & 0x1FFFF, r = pk0 >> 17;
                float4 sv = src[t * 16 + d4];
                float4 wv = w[r * 16 + d4];
                acc.x += sv.x * wv.x; acc.y += sv.y * wv.y;
                acc.z += sv.z * wv.z; acc.w += sv.w * wv.w;
            }
            if (ei1 < m) {
                int t = pk1 & 0x1FFFF, r = pk1 >> 17;
                float4 sv = src[t * 16 + d4];
                float4 wv = w[r * 16 + d4];
                acc.x += sv.x * wv.x; acc.y += sv.y * wv.y;
                acc.z += sv.z * wv.z; acc.w += sv.w * wv.w;
            }
        }
    }
    acc.x += __shfl_xor(acc.x, 16); acc.x += __shfl_xor(acc.x, 32);
    acc.y += __shfl_xor(acc.y, 16); acc.y += __shfl_xor(acc.y, 32);
    acc.z += __shfl_xor(acc.z, 16); acc.z += __shfl_xor(acc.z, 32);
    acc.w += __shfl_xor(acc.w, 16); acc.w += __shfl_xor(acc.w, 32);
    int cnt = e - s;
    float invc = 1.f / (float)(cnt > 1 ? cnt : 1);
    float4 mean = make_float4(acc.x * invc, acc.y * invc, acc.z * invc, acc.w * invc);
    float local = mean.x * mean.x + mean.y * mean.y + mean.z * mean.z + mean.w * mean.w;
    float n2 = wave_sum_f(local) * 0.25f;   // each dim counted 4x (replicated subs)
    float inr = 1.f / fmaxf(sqrtf(n2), 1e-12f);
    if (sub == 0) {
        raw[row * 16 + d4] = mean;
        nrm[row * 16 + d4] = make_float4(mean.x * inr, mean.y * inr, mean.z * inr, mean.w * inr);
    }
}

__global__ void k_agg_node(const float4* __restrict__ u, const float4* __restrict__ ent,
                           const float4* __restrict__ ew,
                           const int* __restrict__ off, const int* __restrict__ csr,
                           float4* __restrict__ node_res, float4* __restrict__ u_out, int store_u) {
    int lane = threadIdx.x & 63;
    int sub = lane >> 4, d4 = lane & 15;
    int row = blockIdx.x * (blockDim.x >> 6) + (threadIdx.x >> 6);
    if (row >= NN) return;
    int s = off[row], e = off[row + 1];
    float4 acc = make_float4(0.f, 0.f, 0.f, 0.f);
    for (int base = s; base < e; base += 64) {
        int m = e - base; if (m > 64) m = 64;
        int p = (lane < m) ? csr[base + lane] : 0;
        int kmax = (m + 7) >> 3;
        for (int k = 0; k < kmax; k++) {
            int ei0 = (k << 3) + sub;
            int ei1 = ei0 + 4;
            int pk0 = __shfl(p, ei0);
            int pk1 = __shfl(p, ei1);
            if (ei0 < m) {
                int t = pk0 & 0x3FFFF, r = pk0 >> 18;
                const float4* srow = (t < NU) ? (u + (size_t)t * 16) : (ent + (size_t)(t - NU) * 16);
                float4 sv = srow[d4];
                float4 wv = ew[r * 16 + d4];
                acc.x += sv.x * wv.x; acc.y += sv.y * wv.y;
                acc.z += sv.z * wv.z; acc.w += sv.w * wv.w;
            }
            if (ei1 < m) {
                int t = pk1 & 0x3FFFF, r = pk1 >> 18;
                const float4* srow = (t < NU) ? (u + (size_t)t * 16) : (ent + (size_t)(t - NU) * 16);
                float4 sv = srow[d4];
                float4 wv = ew[r * 16 + d4];
                acc.x += sv.x * wv.x; acc.y += sv.y * wv.y;
                acc.z += sv.z * wv.z; acc.w += sv.w * wv.w;
            }
        }
    }
    acc.x += __shfl_xor(acc.x, 16); acc.x += __shfl_xor(acc.x, 32);
    acc.y += __shfl_xor(acc.y, 16); acc.y += __shfl_xor(acc.y, 32);
    acc.z += __shfl_xor(acc.z, 16); acc.z += __shfl_xor(acc.z, 32);
    acc.w += __shfl_xor(acc.w, 16); acc.w += __shfl_xor(acc.w, 32);
    int cnt = e - s;
    float invc = 1.f / (float)(cnt > 1 ? cnt : 1);
    float4 mean = make_float4(acc.x * invc, acc.y * invc, acc.z * invc, acc.w * invc);
    float local = mean.x * mean.x + mean.y * mean.y + mean.z * mean.z + mean.w * mean.w;
    float n2 = wave_sum_f(local) * 0.25f;
    float inr = 1.f / fmaxf(sqrtf(n2), 1e-12f);
    if (sub == 0) {
        float4 val = make_float4(mean.x * inr, mean.y * inr, mean.z * inr, mean.w * inr);
        float4 o = node_res[row * 16 + d4];
        o.x += val.x; o.y += val.y; o.z += val.z; o.w += val.w;
        node_res[row * 16 + d4] = o;
        if (store_u && row < NU) u_out[row * 16 + d4] = val;
    }
}

__global__ void k_agg_user(const float4* __restrict__ ent_raw,
                           const int* __restrict__ off, const int2* __restrict__ ccv,
                           float4* __restrict__ user_res) {
    int lane = threadIdx.x & 63;
    int sub = lane >> 4, d4 = lane & 15;
    int row = blockIdx.x * (blockDim.x >> 6) + (threadIdx.x >> 6);
    if (row >= NU) return;
    int s = off[row], e = off[row + 1];
    float4 acc = make_float4(0.f, 0.f, 0.f, 0.f);
    for (int base = s; base < e; base += 64) {
        int m = e - base; if (m > 64) m = 64;
        int2 cv = (lane < m) ? ccv[base + lane] : make_int2(0, 0);
        int c = cv.x;
        float v = __int_as_float(cv.y);
        int kmax = (m + 7) >> 3;
        for (int k = 0; k < kmax; k++) {
            int ei0 = (k << 3) + sub;
            int ei1 = ei0 + 4;
            int c0 = __shfl(c, ei0);
            float v0 = __shfl(v, ei0);
            int c1 = __shfl(c, ei1);
            float v1 = __shfl(v, ei1);
            if (ei0 < m) {
                float4 sv = ent_raw[c0 * 16 + d4];
                acc.x += v0 * sv.x; acc.y += v0 * sv.y;
                acc.z += v0 * sv.z; acc.w += v0 * sv.w;
            }
            if (ei1 < m) {
                float4 sv = ent_raw[c1 * 16 + d4];
                acc.x += v1 * sv.x; acc.y += v1 * sv.y;
                acc.z += v1 * sv.z; acc.w += v1 * sv.w;
            }
        }
    }
    acc.x += __shfl_xor(acc.x, 16); acc.x += __shfl_xor(acc.x, 32);
    acc.y += __shfl_xor(acc.y, 16); acc.y += __shfl_xor(acc.y, 32);
    acc.z += __shfl_xor(acc.z, 16); acc.z += __shfl_xor(acc.z, 32);
    acc.w += __shfl_xor(acc.w, 16); acc.w += __shfl_xor(acc.w, 32);
    float local = acc.x * acc.x + acc.y * acc.y + acc.z * acc.z + acc.w * acc.w;
    float n2 = wave_sum_f(local) * 0.25f;
    float inr = 1.f / fmaxf(sqrtf(n2), 1e-12f);
    if (sub == 0) {
        float4 o = user_res[row * 16 + d4];
        o.x += acc.x * inr; o.y += acc.y * inr;
        o.z += acc.z * inr; o.w += acc.w * inr;
        user_res[row * 16 + d4] = o;
    }
}

extern "C" void kernel_launch(void* const* d_in, const int* in_sizes, int n_in,
                              void* d_out, int out_size, void* d_ws, size_t ws_size,
                              hipStream_t stream) {
    const float* user_emb     = (const float*)d_in[0];
    const float* entity_emb   = (const float*)d_in[1];
    const float* weight       = (const float*)d_in[2];
    const float* extra_weight = (const float*)d_in[3];
    const float* ivals        = (const float*)d_in[4];
    const int* edge_index     = (const int*)d_in[5];
    const int* edge_type      = (const int*)d_in[6];
    const int* xedge_index    = (const int*)d_in[7];
    const int* xedge_type     = (const int*)d_in[8];
    const int* interact_idx   = (const int*)d_in[9];
    float* out = (float*)d_out;

    const int* kg_head = edge_index;
    const int* kg_tail = edge_index + EKG;
    const int* pr_head = xedge_index;
    const int* pr_tail = xedge_index + EPR;
    const int* it_row  = interact_idx;
    const int* it_col  = interact_idx + NNZI;

    char* ws = (char*)d_ws;
    size_t ofs = 0;
    auto take = [&](size_t bytes) -> void* {
        void* p = ws + ofs;
        ofs += (bytes + 255) & ~(size_t)255;
        return p;
    };
    float* ent_raw = (float*)take((size_t)NE * D * 4);
    float* ent_nrm = (float*)take((size_t)NE * D * 4);
    float* uA      = (float*)take((size_t)NU * D * 4);
    int* off_kg = (int*)take((NE + 1) * 4);
    int* off_pr = (int*)take((NN + 1) * 4);
    int* off_it = (int*)take((NU + 1) * 4);
    int* curs   = (int*)take((size_t)(NE + NN + NU + 3) * 4);
    int* cur_kg = curs;
    int* cur_pr = curs + (NE + 1);
    int* cur_it = curs + (NE + 1) + (NN + 1);
    int* csr_kg = (int*)take((size_t)EKG * 4);
    int* csr_pr = (int*)take((size_t)EPR * 4);
    int2* csr_icv = (int2*)take((size_t)NNZI * 8);
    int* bsum = (int*)take(512 * 4);

    // degree histograms (into cur_*) — partitioned by destination range
    hipMemsetAsync(curs, 0, (size_t)(NE + NN + NU + 3) * 4, stream);
    k_hist_part<<<NCHUNK * 8, 256, 0, stream>>>(kg_head, pr_head, it_row, cur_kg, cur_pr, cur_it);

    // exclusive scans -> off_*, cursors reset to off_*
    k_blocksum3<<<NB_KG + NB_PR + NB_IT, 256, 0, stream>>>(cur_kg, cur_pr, cur_it, bsum);
    k_scansums3<<<3, 1, 0, stream>>>(bsum, off_kg + NE, off_pr + NN, off_it + NU);
    k_scanfinal3<<<NB_KG + NB_PR + NB_IT, 1024, 0, stream>>>(cur_kg, cur_pr, cur_it, bsum,
                                                             off_kg, off_pr, off_it,
                                                             cur_kg, cur_pr, cur_it);

    // CSR placement — partitioned by destination range (keeps CSR output lines
    // and cursor atomic lines XCD-local; kills scatter write amplification)
    k_place_part<<<NCHUNK * 8, 256, 0, stream>>>(kg_head, kg_tail, edge_type,
                                                 pr_head, pr_tail, xedge_type,
                                                 it_row, it_col, ivals,
                                                 cur_kg, cur_pr, cur_it,
                                                 csr_kg, csr_pr, csr_icv);

    // init residual accumulators in d_out
    k_init<<<(NU * D + 255) / 256, 256, 0, stream>>>(user_emb, entity_emb, out);

    const int RPB = 4;  // waves (rows) per 256-thread block

    const float4* user4 = (const float4*)user_emb;
    const float4* ent4  = (const float4*)entity_emb;
    const float4* w4    = (const float4*)weight;
    const float4* ew4   = (const float4*)extra_weight;

    // hop 1
    k_agg_entity<<<(NE + RPB - 1) / RPB, 256, 0, stream>>>(ent4, w4, off_kg, csr_kg,
                                                           (float4*)ent_raw, (float4*)ent_nrm);
    k_agg_node<<<(NN + RPB - 1) / RPB, 256, 0, stream>>>(user4, ent4, ew4, off_pr, csr_pr,
                                                         (float4*)(out + NODE_BASE), (float4*)uA, 1);
    k_agg_user<<<(NU + RPB - 1) / RPB, 256, 0, stream>>>((const float4*)ent_raw, off_it, csr_icv,
                                                         (float4*)out);

    // hop 2
    k_agg_entity<<<(NE + RPB - 1) / RPB, 256, 0, stream>>>((const float4*)ent_nrm, w4, off_kg, csr_kg,
                                                           (float4*)ent_raw, (float4*)(out + GCN_ENT_BASE));
    k_agg_node<<<(NN + RPB - 1) / RPB, 256, 0, stream>>>((const float4*)uA, (const float4*)ent_nrm, ew4,
                                                         off_pr, csr_pr,
                                                         (float4*)(out + NODE_BASE), nullptr, 0);
    k_agg_user<<<(NU + RPB - 1) / RPB, 256, 0, stream>>>((const float4*)ent_raw, off_it, csr_icv,
                                                         (float4*)out);
}